// Round 6
// baseline (272.050 us; speedup 1.0000x reference)
//
#include <hip/hip_runtime.h>
#include <math.h>

// Problem constants (from reference)
#define NPATCH 8192
#define KC     10
#define DIN    1024
#define DH     512
#define DA     256
#define NCLS   4

#define TM  64    // patches per phi block (64-row M-tile; LDS 66.5 KB static, 2 blocks/CU)
#define LDA 520   // padded LDS row stride (u16): 1040 B -> b128 frag reads spread all banks

typedef unsigned short u16;
typedef short bf16x8 __attribute__((ext_vector_type(8)));   // 8 bf16 = 4 VGPRs
typedef float f32x4  __attribute__((ext_vector_type(4)));

// Workspace layout (bytes)
#define OFF_CNT   0                  // int[KC] (64B)
#define OFF_IDX   64                 // int[KC*NPATCH]
#define OFF_PSUM  327744             // float[KC*DH]
#define OFF_H     348224             // float[KC*DH]
#define OFF_S     368704             // float[KC] (64B)
#define OFF_W1P   368768             // u16[KC*DIN*DH]
#define OFF_W2P   10854528           // u16[KC*DH*DH]
#define OFF_XB    16097408           // u16[NPATCH*DIN]
#define OFF_H1    32874624           // u16[NPATCH*DH]
// total ~41.3 MB

__device__ __forceinline__ u16 f2bf(float f) {
  union { float f; unsigned u; } v; v.f = f;
  unsigned r = (v.u + 0x7fffu + ((v.u >> 16) & 1u)) >> 16;  // RNE
  return (u16)r;
}

struct __align__(8) U16x4 { u16 x, y, z, w; };

// Async global->LDS DMA, 16B/lane; per-lane global addr, LDS dest = base + lane*16.
__device__ __forceinline__ void async16(const void* gp, void* lp) {
  __builtin_amdgcn_global_load_lds(
      (const __attribute__((address_space(1))) void*)gp,
      (__attribute__((address_space(3))) void*)lp, 16, 0, 0);
}

#define W1_TILES (KC * (DIN / 32) * (DH / 32))  // 5120
#define W2_TILES (KC * (DH / 32) * (DH / 32))   // 2560
#define NB_BUCKET 32
#define NB_XB     2048
#define NB_PREP   (NB_BUCKET + W1_TILES + W2_TILES + NB_XB)  // 9760

// Fused prep: bucket + zero psum (blocks 0..31), pack W1/W2 -> bf16 MFMA-B
// panels [k][kb][n][ki], pack x -> bf16 row-major.
__global__ __launch_bounds__(256) void prep_kernel(
    const int* __restrict__ cid, int* __restrict__ cnt,
    int* __restrict__ idxlist, const float* __restrict__ W1,
    const float* __restrict__ W2, u16* __restrict__ W1p,
    u16* __restrict__ W2p, const float* __restrict__ x,
    u16* __restrict__ xb, float* __restrict__ psum) {
  int b = blockIdx.x, t = threadIdx.x;
  if (b < NB_BUCKET) {
    int g = b * 256 + t;
    if (g < KC * DH) psum[g] = 0.f;
    __shared__ int lcnt[KC], lbase[KC];
    if (t < KC) lcnt[t] = 0;
    __syncthreads();
    int n = b * 256 + t;                 // NPATCH == 32*256
    int k = cid[n];
    int myoff = atomicAdd(&lcnt[k], 1);
    __syncthreads();
    if (t < KC) lbase[t] = atomicAdd(&cnt[t], lcnt[t]);
    __syncthreads();
    idxlist[k * NPATCH + lbase[k] + myoff] = n;
  } else if (b < NB_BUCKET + W1_TILES + W2_TILES) {
    __shared__ u16 tile[32][33];
    int bb = b - NB_BUCKET;
    const float* src;
    u16* dst;
    if (bb < W1_TILES) {
      int k = bb / 512, rem = bb % 512;
      int kb = rem / 16, n0 = (rem % 16) * 32;
      src = W1 + (size_t)k * DIN * DH + (size_t)kb * 32 * DH + n0;
      dst = W1p + (((size_t)(k * 32 + kb) * 512 + n0) * 32);
    } else {
      int b2 = bb - W1_TILES;
      int k = b2 / 256, rem = b2 % 256;
      int kb = rem / 16, n0 = (rem % 16) * 32;
      src = W2 + (size_t)k * DH * DH + (size_t)kb * 32 * DH + n0;
      dst = W2p + (((size_t)(k * 16 + kb) * 512 + n0) * 32);
    }
    {
      int ki = t >> 3, n4 = (t & 7) * 4;
      float4 v = *(const float4*)&src[(size_t)ki * DH + n4];
      tile[ki][n4 + 0] = f2bf(v.x);
      tile[ki][n4 + 1] = f2bf(v.y);
      tile[ki][n4 + 2] = f2bf(v.z);
      tile[ki][n4 + 3] = f2bf(v.w);
    }
    __syncthreads();
    {
      int n = t >> 3, ki = (t & 7) * 4;
      U16x4 o = {tile[ki + 0][n], tile[ki + 1][n], tile[ki + 2][n],
                 tile[ki + 3][n]};
      *(U16x4*)&dst[(size_t)n * 32 + ki] = o;
    }
  } else {
    int cb = b - (NB_BUCKET + W1_TILES + W2_TILES);
    size_t basei = (size_t)cb * 4096;
#pragma unroll
    for (int i = 0; i < 4; ++i) {
      size_t off = basei + (size_t)i * 1024 + (size_t)t * 4;
      float4 v = *(const float4*)(x + off);
      U16x4 o = {f2bf(v.x), f2bf(v.y), f2bf(v.z), f2bf(v.w)};
      *(U16x4*)(xb + off) = o;
    }
  }
}

// Layer 1: h1 = relu(x @ W1[k] + b1[k]), bf16 out. grid (128, KC, 4):
// 64-patch chunk, cluster, 128-col quarter. Wave w owns 32 cols; acc 4mt x 2nt.
// B prefetch: double-buffered groups of 4 ks.
__global__ __launch_bounds__(256) void phi1_kernel(
    const u16* __restrict__ xb, const u16* __restrict__ W1p,
    const float* __restrict__ b1, const int* __restrict__ cnt,
    const int* __restrict__ idxlist, u16* __restrict__ h1) {
  const int k = blockIdx.y;
  const int base = blockIdx.x * TM;
  const int nq = blockIdx.z;
  const int cntk = cnt[k];
  if (base >= cntk) return;

  const int tid = threadIdx.x;
  const int w = tid >> 6, lane = tid & 63;
  const int quad = lane >> 4, l16 = lane & 15;

  __shared__ __align__(16) u16 A_sh[TM * LDA];  // 66.56 KB
  __shared__ int ridx[TM];
  if (tid < TM) {
    int r = base + tid;
    ridx[tid] = (r < cntk) ? idxlist[k * NPATCH + r] : -1;
  }
  __syncthreads();

  const f32x4 zero4 = {0.f, 0.f, 0.f, 0.f};
  f32x4 acc[4][2];
#pragma unroll
  for (int m = 0; m < 4; ++m)
#pragma unroll
    for (int nt = 0; nt < 2; ++nt) acc[m][nt] = zero4;

  for (int kh = 0; kh < 2; ++kh) {
    if (kh) __syncthreads();
    // stage 16 rows per wave via DMA (1 KB half-row each), zero-fill padded
    for (int rr = 0; rr < 16; ++rr) {
      int r = w * 16 + rr;
      int src = ridx[r];
      if (src >= 0) {
        async16(xb + (size_t)src * DIN + kh * 512 + lane * 8, &A_sh[r * LDA]);
      } else {
        bf16x8 z = {0, 0, 0, 0, 0, 0, 0, 0};
        *(bf16x8*)&A_sh[r * LDA + lane * 8] = z;
      }
    }
    __syncthreads();

    // B: col = nq*128 + w*32 + l16; ks stride 16384 u16, nt stride 512 u16
    const u16* wb = W1p + ((size_t)(k * 32 + kh * 16) * 512 +
                           (nq * 128 + w * 32 + l16)) * 32 + quad * 8;
    bf16x8 B[2][8];
#pragma unroll
    for (int s = 0; s < 4; ++s)
#pragma unroll
      for (int nt = 0; nt < 2; ++nt)
        B[0][s * 2 + nt] = *(const bf16x8*)(wb + (size_t)s * 16384 + nt * 512);
#pragma unroll
    for (int g = 0; g < 4; ++g) {
      const int cur = g & 1, nxt = cur ^ 1;
      if (g < 3) {
#pragma unroll
        for (int s = 0; s < 4; ++s)
#pragma unroll
          for (int nt = 0; nt < 2; ++nt)
            B[nxt][s * 2 + nt] = *(const bf16x8*)(
                wb + (size_t)((g + 1) * 4 + s) * 16384 + nt * 512);
      }
#pragma unroll
      for (int s = 0; s < 4; ++s) {
        const int ks = g * 4 + s;
        bf16x8 af[4];
#pragma unroll
        for (int m = 0; m < 4; ++m)
          af[m] = *(const bf16x8*)&A_sh[(m * 16 + l16) * LDA + ks * 32 + quad * 8];
#pragma unroll
        for (int m = 0; m < 4; ++m)
#pragma unroll
          for (int nt = 0; nt < 2; ++nt)
            acc[m][nt] = __builtin_amdgcn_mfma_f32_16x16x32_bf16(
                af[m], B[cur][s * 2 + nt], acc[m][nt], 0, 0, 0);
      }
    }
  }

  // epilogue: bias+relu -> bf16 via LDS transpose (stride 136) -> h1 writes
  __syncthreads();
#pragma unroll
  for (int m = 0; m < 4; ++m)
#pragma unroll
    for (int nt = 0; nt < 2; ++nt) {
      int c = w * 32 + nt * 16 + l16;
      float bias = b1[k * DH + nq * 128 + c];
#pragma unroll
      for (int r = 0; r < 4; ++r) {
        int row = m * 16 + quad * 4 + r;
        A_sh[row * 136 + c] = f2bf(fmaxf(acc[m][nt][r] + bias, 0.f));
      }
    }
  __syncthreads();
  {
    int row = tid >> 2, seg = tid & 3;
    int n = ridx[row];
    if (n >= 0) {
      u16* dst = h1 + (size_t)n * DH + nq * 128 + seg * 32;
#pragma unroll
      for (int j = 0; j < 4; ++j)
        *(bf16x8*)(dst + j * 8) =
            *(const bf16x8*)&A_sh[row * 136 + seg * 32 + j * 8];
    }
  }
}

// Layer 2 + masked mean-pool numerator: psum[k] += relu(h1 @ W2[k] + b2[k]).
// grid (128, KC, 4), TM=64, 128-col quarters.
__global__ __launch_bounds__(256) void phi2_kernel(
    const u16* __restrict__ h1, const u16* __restrict__ W2p,
    const float* __restrict__ b2, const int* __restrict__ cnt,
    const int* __restrict__ idxlist, float* __restrict__ psum) {
  const int k = blockIdx.y;
  const int base = blockIdx.x * TM;
  const int nq = blockIdx.z;
  const int cntk = cnt[k];
  if (base >= cntk) return;

  const int tid = threadIdx.x;
  const int w = tid >> 6, lane = tid & 63;
  const int quad = lane >> 4, l16 = lane & 15;

  __shared__ __align__(16) u16 H_sh[TM * LDA];
  __shared__ int ridx[TM];
  if (tid < TM) {
    int r = base + tid;
    ridx[tid] = (r < cntk) ? idxlist[k * NPATCH + r] : -1;
  }
  __syncthreads();

  for (int rr = 0; rr < 16; ++rr) {
    int r = w * 16 + rr;
    int src = ridx[r];
    if (src >= 0) {
      async16(h1 + (size_t)src * DH + lane * 8, &H_sh[r * LDA]);
    } else {
      bf16x8 z = {0, 0, 0, 0, 0, 0, 0, 0};
      *(bf16x8*)&H_sh[r * LDA + lane * 8] = z;
    }
  }
  __syncthreads();

  const f32x4 zero4 = {0.f, 0.f, 0.f, 0.f};
  f32x4 acc[4][2];
#pragma unroll
  for (int m = 0; m < 4; ++m)
#pragma unroll
    for (int nt = 0; nt < 2; ++nt) acc[m][nt] = zero4;

  const u16* wb = W2p + ((size_t)(k * 16) * 512 +
                         (nq * 128 + w * 32 + l16)) * 32 + quad * 8;
  bf16x8 B[2][8];
#pragma unroll
  for (int s = 0; s < 4; ++s)
#pragma unroll
    for (int nt = 0; nt < 2; ++nt)
      B[0][s * 2 + nt] = *(const bf16x8*)(wb + (size_t)s * 16384 + nt * 512);
#pragma unroll
  for (int g = 0; g < 4; ++g) {
    const int cur = g & 1, nxt = cur ^ 1;
    if (g < 3) {
#pragma unroll
      for (int s = 0; s < 4; ++s)
#pragma unroll
        for (int nt = 0; nt < 2; ++nt)
          B[nxt][s * 2 + nt] = *(const bf16x8*)(
              wb + (size_t)((g + 1) * 4 + s) * 16384 + nt * 512);
    }
#pragma unroll
    for (int s = 0; s < 4; ++s) {
      const int ks = g * 4 + s;
      bf16x8 af[4];
#pragma unroll
      for (int m = 0; m < 4; ++m)
        af[m] = *(const bf16x8*)&H_sh[(m * 16 + l16) * LDA + ks * 32 + quad * 8];
#pragma unroll
      for (int m = 0; m < 4; ++m)
#pragma unroll
        for (int nt = 0; nt < 2; ++nt)
          acc[m][nt] = __builtin_amdgcn_mfma_f32_16x16x32_bf16(
              af[m], B[cur][s * 2 + nt], acc[m][nt], 0, 0, 0);
    }
  }

  float vmask[4][4];
#pragma unroll
  for (int m = 0; m < 4; ++m)
#pragma unroll
    for (int r = 0; r < 4; ++r)
      vmask[m][r] = (ridx[m * 16 + quad * 4 + r] >= 0) ? 1.f : 0.f;

#pragma unroll
  for (int nt = 0; nt < 2; ++nt) {
    int col = nq * 128 + w * 32 + nt * 16 + l16;
    float bias = b2[k * DH + col];
    float s = 0.f;
#pragma unroll
    for (int m = 0; m < 4; ++m)
#pragma unroll
      for (int r = 0; r < 4; ++r)
        s += vmask[m][r] * fmaxf(acc[m][nt][r] + bias, 0.f);
    s += __shfl_xor(s, 16, 64);
    s += __shfl_xor(s, 32, 64);
    if (quad == 0) atomicAdd(&psum[k * DH + col], s);
  }
}

// Fused head: pooled mean -> fc+relu -> gated attention score. grid KC.
__global__ __launch_bounds__(256) void head_kernel(
    const float* __restrict__ psum, const int* __restrict__ cnt,
    const float* __restrict__ fcW, const float* __restrict__ fcb,
    const float* __restrict__ Va, const float* __restrict__ ba,
    const float* __restrict__ Vb, const float* __restrict__ bb_,
    const float* __restrict__ Vc, float* __restrict__ hstore,
    float* __restrict__ sstore) {
  int k = blockIdx.x, tid = threadIdx.x;
  __shared__ float p_sh[DH], h_sh[DH];
  __shared__ float red[256];
  int c = cnt[k];
  float inv = (c > 0) ? 1.f / (float)c : 0.f;
  for (int d = tid; d < DH; d += 256) p_sh[d] = psum[k * DH + d] * inv;
  __syncthreads();

#pragma unroll
  for (int jj = 0; jj < 2; ++jj) {
    int j = jj * 256 + tid;
    float s[8] = {0.f, 0.f, 0.f, 0.f, 0.f, 0.f, 0.f, 0.f};
    for (int d = 0; d < DH; d += 8) {
#pragma unroll
      for (int u = 0; u < 8; ++u)
        s[u] = fmaf(p_sh[d + u], fcW[(size_t)(d + u) * DH + j], s[u]);
    }
    float t0 = (s[0] + s[1]) + (s[2] + s[3]),
          t1 = (s[4] + s[5]) + (s[6] + s[7]);
    float h = fmaxf(t0 + t1 + fcb[j], 0.f);
    h_sh[j] = h;
    hstore[k * DH + j] = h;
  }
  __syncthreads();

  {
    int j = tid;  // DA == 256
    float sa[4] = {0.f, 0.f, 0.f, 0.f}, sb[4] = {0.f, 0.f, 0.f, 0.f};
    for (int d = 0; d < DH; d += 4) {
#pragma unroll
      for (int u = 0; u < 4; ++u) {
        float h = h_sh[d + u];
        sa[u] = fmaf(h, Va[(size_t)(d + u) * DA + j], sa[u]);
        sb[u] = fmaf(h, Vb[(size_t)(d + u) * DA + j], sb[u]);
      }
    }
    float a = tanhf((sa[0] + sa[1]) + (sa[2] + sa[3]) + ba[j]);
    float b = 1.f / (1.f + expf(-((sb[0] + sb[1]) + (sb[2] + sb[3]) + bb_[j])));
    red[tid] = a * b * Vc[j];  // bc dropped: softmax shift-invariant
  }
  __syncthreads();
  for (int s = 128; s > 0; s >>= 1) {
    if (tid < s) red[tid] += red[tid + s];
    __syncthreads();
  }
  if (tid == 0) sstore[k] = red[0];
}

// softmax over K -> h_path -> rho -> classifier -> hazards/S/Y_hat. 1 block.
__global__ __launch_bounds__(256) void tail_kernel(
    const float* __restrict__ hstore, const float* __restrict__ sstore,
    const float* __restrict__ rhoW, const float* __restrict__ rhob,
    const float* __restrict__ clsW, const float* __restrict__ clsb,
    float* __restrict__ out) {
  int tid = threadIdx.x;
  __shared__ float hp_sh[DH];
  __shared__ float h2_sh[DA];
  __shared__ float lg[NCLS];

  float sv[KC];
  float m = -1e30f;
#pragma unroll
  for (int k = 0; k < KC; ++k) {
    sv[k] = sstore[k];
    m = fmaxf(m, sv[k]);
  }
  float Z = 0.f;
#pragma unroll
  for (int k = 0; k < KC; ++k) {
    sv[k] = expf(sv[k] - m);
    Z += sv[k];
  }
  float invZ = 1.f / Z;

#pragma unroll
  for (int jj = 0; jj < 2; ++jj) {
    int d = tid + jj * 256;
    float s = 0.f;
#pragma unroll
    for (int k = 0; k < KC; ++k) s = fmaf(sv[k] * invZ, hstore[k * DH + d], s);
    hp_sh[d] = s;
  }
  __syncthreads();

  if (tid < DA) {
    float s[8] = {0.f, 0.f, 0.f, 0.f, 0.f, 0.f, 0.f, 0.f};
    for (int d = 0; d < DH; d += 8) {
#pragma unroll
      for (int u = 0; u < 8; ++u)
        s[u] = fmaf(hp_sh[d + u], rhoW[(size_t)(d + u) * DA + tid], s[u]);
    }
    float t0 = (s[0] + s[1]) + (s[2] + s[3]),
          t1 = (s[4] + s[5]) + (s[6] + s[7]);
    h2_sh[tid] = fmaxf(t0 + t1 + rhob[tid], 0.f);
  }
  __syncthreads();

  if (tid < NCLS) {
    float s[4] = {0.f, 0.f, 0.f, 0.f};
    for (int d = 0; d < DA; d += 4) {
#pragma unroll
      for (int u = 0; u < 4; ++u)
        s[u] = fmaf(h2_sh[d + u], clsW[(size_t)(d + u) * NCLS + tid], s[u]);
    }
    lg[tid] = (s[0] + s[1]) + (s[2] + s[3]) + clsb[tid];
  }
  __syncthreads();

  if (tid == 0) {
    float hz[NCLS];
    int best = 0;
#pragma unroll
    for (int c = 0; c < NCLS; ++c) {
      hz[c] = 1.f / (1.f + expf(-lg[c]));
      if (lg[c] > lg[best]) best = c;
    }
    float S = 1.f;
#pragma unroll
    for (int c = 0; c < NCLS; ++c) out[c] = hz[c];
#pragma unroll
    for (int c = 0; c < NCLS; ++c) {
      S *= (1.f - hz[c]);
      out[NCLS + c] = S;
    }
    out[2 * NCLS] = (float)best;
  }
}

extern "C" void kernel_launch(void* const* d_in, const int* in_sizes, int n_in,
                              void* d_out, int out_size, void* d_ws,
                              size_t ws_size, hipStream_t stream) {
  const float* x    = (const float*)d_in[0];
  const int*   cid  = (const int*)d_in[1];
  const float* W1   = (const float*)d_in[2];
  const float* b1   = (const float*)d_in[3];
  const float* W2   = (const float*)d_in[4];
  const float* b2   = (const float*)d_in[5];
  const float* fcW  = (const float*)d_in[6];
  const float* fcb  = (const float*)d_in[7];
  const float* Va   = (const float*)d_in[8];
  const float* ba   = (const float*)d_in[9];
  const float* Vb   = (const float*)d_in[10];
  const float* bb_  = (const float*)d_in[11];
  const float* Vc   = (const float*)d_in[12];
  const float* rhoW = (const float*)d_in[14];
  const float* rhob = (const float*)d_in[15];
  const float* clsW = (const float*)d_in[16];
  const float* clsb = (const float*)d_in[17];
  float* out = (float*)d_out;

  char* ws = (char*)d_ws;
  int*   cnt     = (int*)(ws + OFF_CNT);
  int*   idxlist = (int*)(ws + OFF_IDX);
  float* psum    = (float*)(ws + OFF_PSUM);
  float* hstore  = (float*)(ws + OFF_H);
  float* sstore  = (float*)(ws + OFF_S);
  u16*   W1p     = (u16*)(ws + OFF_W1P);
  u16*   W2p     = (u16*)(ws + OFF_W2P);
  u16*   xb      = (u16*)(ws + OFF_XB);
  u16*   h1      = (u16*)(ws + OFF_H1);

  (void)hipMemsetAsync(cnt, 0, 64, stream);
  prep_kernel<<<NB_PREP, 256, 0, stream>>>(cid, cnt, idxlist, W1, W2, W1p, W2p,
                                           x, xb, psum);
  phi1_kernel<<<dim3(NPATCH / TM, KC, 4), 256, 0, stream>>>(xb, W1p, b1, cnt,
                                                            idxlist, h1);
  phi2_kernel<<<dim3(NPATCH / TM, KC, 4), 256, 0, stream>>>(h1, W2p, b2, cnt,
                                                            idxlist, psum);
  head_kernel<<<KC, 256, 0, stream>>>(psum, cnt, fcW, fcb, Va, ba, Vb, bb_, Vc,
                                      hstore, sstore);
  tail_kernel<<<1, 256, 0, stream>>>(hstore, sstore, rhoW, rhob, clsW, clsb, out);
}

// Round 7
// 202.231 us; speedup vs baseline: 1.3452x; 1.3452x over previous
//
#include <hip/hip_runtime.h>
#include <math.h>

// Problem constants (from reference)
#define NPATCH 8192
#define KC     10
#define DIN    1024
#define DH     512
#define DA     256
#define NCLS   4

#define TM  32    // patches per phi block
#define LDA 520   // padded LDS row stride (u16): 1040 B spreads b128 frag reads over banks

typedef unsigned short u16;
typedef short bf16x8 __attribute__((ext_vector_type(8)));   // 8 bf16 = 4 VGPRs
typedef float f32x4  __attribute__((ext_vector_type(4)));

// Workspace layout (bytes)
#define OFF_CNT   0                  // int[KC] (64B)
#define OFF_IDX   64                 // int[KC*NPATCH]
#define OFF_PSUM  327744             // float[KC*DH]
#define OFF_H     348224             // float[KC*DH]
#define OFF_S     368704             // float[KC] (64B)
#define OFF_H2    368768             // float[DA] (1KB)
#define OFF_W1P   369792             // u16[KC*DIN*DH]
#define OFF_W2P   10855552           // u16[KC*DH*DH]
#define OFF_XB    16098432           // u16[NPATCH*DIN]
#define OFF_H1    32875648           // u16[NPATCH*DH]
// total ~41.3 MB

__device__ __forceinline__ u16 f2bf(float f) {
  union { float f; unsigned u; } v; v.f = f;
  unsigned r = (v.u + 0x7fffu + ((v.u >> 16) & 1u)) >> 16;  // RNE
  return (u16)r;
}

struct __align__(8) U16x4 { u16 x, y, z, w; };

// Async global->LDS DMA, 16B/lane; LDS dest = wave-uniform base + lane*16.
__device__ __forceinline__ void async16(const void* gp, void* lp) {
  __builtin_amdgcn_global_load_lds(
      (const __attribute__((address_space(1))) void*)gp,
      (__attribute__((address_space(3))) void*)lp, 16, 0, 0);
}

#define W1_TILES (KC * (DIN / 32) * (DH / 32))  // 5120
#define W2_TILES (KC * (DH / 32) * (DH / 32))   // 2560
#define NB_BUCKET 32
#define NB_XB     2048
#define NB_PREP   (NB_BUCKET + W1_TILES + W2_TILES + NB_XB)  // 9760

// Fused prep: bucket + zero psum/sstore (blocks 0..31), pack W1/W2 -> bf16
// MFMA-B panels [k][kb][n][ki], pack x -> bf16 row-major.
__global__ __launch_bounds__(256) void prep_kernel(
    const int* __restrict__ cid, int* __restrict__ cnt,
    int* __restrict__ idxlist, const float* __restrict__ W1,
    const float* __restrict__ W2, u16* __restrict__ W1p,
    u16* __restrict__ W2p, const float* __restrict__ x,
    u16* __restrict__ xb, float* __restrict__ psum,
    float* __restrict__ sstore) {
  int b = blockIdx.x, t = threadIdx.x;
  if (b < NB_BUCKET) {
    int g = b * 256 + t;
    if (g < KC * DH) psum[g] = 0.f;
    if (g < KC) sstore[g] = 0.f;
    __shared__ int lcnt[KC], lbase[KC];
    if (t < KC) lcnt[t] = 0;
    __syncthreads();
    int n = b * 256 + t;                 // NPATCH == 32*256
    int k = cid[n];
    int myoff = atomicAdd(&lcnt[k], 1);
    __syncthreads();
    if (t < KC) lbase[t] = atomicAdd(&cnt[t], lcnt[t]);
    __syncthreads();
    idxlist[k * NPATCH + lbase[k] + myoff] = n;
  } else if (b < NB_BUCKET + W1_TILES + W2_TILES) {
    __shared__ u16 tile[32][33];
    int bb = b - NB_BUCKET;
    const float* src;
    u16* dst;
    if (bb < W1_TILES) {
      int k = bb / 512, rem = bb % 512;
      int kb = rem / 16, n0 = (rem % 16) * 32;
      src = W1 + (size_t)k * DIN * DH + (size_t)kb * 32 * DH + n0;
      dst = W1p + (((size_t)(k * 32 + kb) * 512 + n0) * 32);
    } else {
      int b2 = bb - W1_TILES;
      int k = b2 / 256, rem = b2 % 256;
      int kb = rem / 16, n0 = (rem % 16) * 32;
      src = W2 + (size_t)k * DH * DH + (size_t)kb * 32 * DH + n0;
      dst = W2p + (((size_t)(k * 16 + kb) * 512 + n0) * 32);
    }
    {
      int ki = t >> 3, n4 = (t & 7) * 4;
      float4 v = *(const float4*)&src[(size_t)ki * DH + n4];
      tile[ki][n4 + 0] = f2bf(v.x);
      tile[ki][n4 + 1] = f2bf(v.y);
      tile[ki][n4 + 2] = f2bf(v.z);
      tile[ki][n4 + 3] = f2bf(v.w);
    }
    __syncthreads();
    {
      int n = t >> 3, ki = (t & 7) * 4;
      U16x4 o = {tile[ki + 0][n], tile[ki + 1][n], tile[ki + 2][n],
                 tile[ki + 3][n]};
      *(U16x4*)&dst[(size_t)n * 32 + ki] = o;
    }
  } else {
    int cb = b - (NB_BUCKET + W1_TILES + W2_TILES);
    size_t basei = (size_t)cb * 4096;
#pragma unroll
    for (int i = 0; i < 4; ++i) {
      size_t off = basei + (size_t)i * 1024 + (size_t)t * 4;
      float4 v = *(const float4*)(x + off);
      U16x4 o = {f2bf(v.x), f2bf(v.y), f2bf(v.z), f2bf(v.w)};
      *(U16x4*)(xb + off) = o;
    }
  }
}

// Layer 1: h1 = relu(x @ W1[k] + b1[k]), bf16 out. grid (256, KC, 4):
// 32-patch chunk, cluster, 128-col quarter. Wave w owns 32 cols; acc 2mt x 2nt.
// B prefetch: double-buffered groups of 4 ks. ~1024 working blocks, 4/CU.
__global__ __launch_bounds__(256) void phi1_kernel(
    const u16* __restrict__ xb, const u16* __restrict__ W1p,
    const float* __restrict__ b1, const int* __restrict__ cnt,
    const int* __restrict__ idxlist, u16* __restrict__ h1) {
  const int k = blockIdx.y;
  const int base = blockIdx.x * TM;
  const int nq = blockIdx.z;
  const int cntk = cnt[k];
  if (base >= cntk) return;

  const int tid = threadIdx.x;
  const int w = tid >> 6, lane = tid & 63;
  const int quad = lane >> 4, l16 = lane & 15;

  __shared__ __align__(16) u16 A_sh[TM * LDA];  // 33.3 KB
  __shared__ int ridx[TM];
  if (tid < TM) {
    int r = base + tid;
    ridx[tid] = (r < cntk) ? idxlist[k * NPATCH + r] : -1;
  }
  __syncthreads();

  const f32x4 zero4 = {0.f, 0.f, 0.f, 0.f};
  f32x4 acc[2][2];
#pragma unroll
  for (int m = 0; m < 2; ++m)
#pragma unroll
    for (int nt = 0; nt < 2; ++nt) acc[m][nt] = zero4;

  for (int kh = 0; kh < 2; ++kh) {
    if (kh) __syncthreads();
    for (int rr = 0; rr < 8; ++rr) {
      int r = w * 8 + rr;
      int src = ridx[r];
      if (src >= 0) {
        async16(xb + (size_t)src * DIN + kh * 512 + lane * 8, &A_sh[r * LDA]);
      } else {
        bf16x8 z = {0, 0, 0, 0, 0, 0, 0, 0};
        *(bf16x8*)&A_sh[r * LDA + lane * 8] = z;
      }
    }
    __syncthreads();

    // B: col = nq*128 + w*32 + l16; ks stride 16384 u16, nt stride 512 u16
    const u16* wb = W1p + ((size_t)(k * 32 + kh * 16) * 512 +
                           (nq * 128 + w * 32 + l16)) * 32 + quad * 8;
    bf16x8 B[2][8];
#pragma unroll
    for (int s = 0; s < 4; ++s)
#pragma unroll
      for (int nt = 0; nt < 2; ++nt)
        B[0][s * 2 + nt] = *(const bf16x8*)(wb + (size_t)s * 16384 + nt * 512);
#pragma unroll
    for (int g = 0; g < 4; ++g) {
      const int cur = g & 1, nxt = cur ^ 1;
      if (g < 3) {
#pragma unroll
        for (int s = 0; s < 4; ++s)
#pragma unroll
          for (int nt = 0; nt < 2; ++nt)
            B[nxt][s * 2 + nt] = *(const bf16x8*)(
                wb + (size_t)((g + 1) * 4 + s) * 16384 + nt * 512);
      }
#pragma unroll
      for (int s = 0; s < 4; ++s) {
        const int ks = g * 4 + s;
        bf16x8 af0 = *(const bf16x8*)&A_sh[l16 * LDA + ks * 32 + quad * 8];
        bf16x8 af1 =
            *(const bf16x8*)&A_sh[(16 + l16) * LDA + ks * 32 + quad * 8];
#pragma unroll
        for (int nt = 0; nt < 2; ++nt) {
          acc[0][nt] = __builtin_amdgcn_mfma_f32_16x16x32_bf16(
              af0, B[cur][s * 2 + nt], acc[0][nt], 0, 0, 0);
          acc[1][nt] = __builtin_amdgcn_mfma_f32_16x16x32_bf16(
              af1, B[cur][s * 2 + nt], acc[1][nt], 0, 0, 0);
        }
      }
    }
  }

  // epilogue: bias+relu -> bf16 via LDS transpose (stride 136) -> h1 writes
  __syncthreads();
#pragma unroll
  for (int m = 0; m < 2; ++m)
#pragma unroll
    for (int nt = 0; nt < 2; ++nt) {
      int c = w * 32 + nt * 16 + l16;
      float bias = b1[k * DH + nq * 128 + c];
#pragma unroll
      for (int r = 0; r < 4; ++r) {
        int row = m * 16 + quad * 4 + r;
        A_sh[row * 136 + c] = f2bf(fmaxf(acc[m][nt][r] + bias, 0.f));
      }
    }
  __syncthreads();
  {
    int row = tid >> 3, seg = tid & 7;   // 32 rows x 8 segs x 16 u16
    int n = ridx[row];
    if (n >= 0) {
      u16* dst = h1 + (size_t)n * DH + nq * 128 + seg * 16;
#pragma unroll
      for (int j = 0; j < 2; ++j)
        *(bf16x8*)(dst + j * 8) =
            *(const bf16x8*)&A_sh[row * 136 + seg * 16 + j * 8];
    }
  }
}

// Layer 2 + masked mean-pool numerator: psum[k] += relu(h1 @ W2[k] + b2[k]).
// grid (256, KC, 4), TM=32, 128-col quarters.
__global__ __launch_bounds__(256) void phi2_kernel(
    const u16* __restrict__ h1, const u16* __restrict__ W2p,
    const float* __restrict__ b2, const int* __restrict__ cnt,
    const int* __restrict__ idxlist, float* __restrict__ psum) {
  const int k = blockIdx.y;
  const int base = blockIdx.x * TM;
  const int nq = blockIdx.z;
  const int cntk = cnt[k];
  if (base >= cntk) return;

  const int tid = threadIdx.x;
  const int w = tid >> 6, lane = tid & 63;
  const int quad = lane >> 4, l16 = lane & 15;

  __shared__ __align__(16) u16 H_sh[TM * LDA];
  __shared__ int ridx[TM];
  if (tid < TM) {
    int r = base + tid;
    ridx[tid] = (r < cntk) ? idxlist[k * NPATCH + r] : -1;
  }
  __syncthreads();

  for (int rr = 0; rr < 8; ++rr) {
    int r = w * 8 + rr;
    int src = ridx[r];
    if (src >= 0) {
      async16(h1 + (size_t)src * DH + lane * 8, &H_sh[r * LDA]);
    } else {
      bf16x8 z = {0, 0, 0, 0, 0, 0, 0, 0};
      *(bf16x8*)&H_sh[r * LDA + lane * 8] = z;
    }
  }
  __syncthreads();

  const f32x4 zero4 = {0.f, 0.f, 0.f, 0.f};
  f32x4 acc[2][2];
#pragma unroll
  for (int m = 0; m < 2; ++m)
#pragma unroll
    for (int nt = 0; nt < 2; ++nt) acc[m][nt] = zero4;

  const u16* wb = W2p + ((size_t)(k * 16) * 512 +
                         (nq * 128 + w * 32 + l16)) * 32 + quad * 8;
  bf16x8 B[2][8];
#pragma unroll
  for (int s = 0; s < 4; ++s)
#pragma unroll
    for (int nt = 0; nt < 2; ++nt)
      B[0][s * 2 + nt] = *(const bf16x8*)(wb + (size_t)s * 16384 + nt * 512);
#pragma unroll
  for (int g = 0; g < 4; ++g) {
    const int cur = g & 1, nxt = cur ^ 1;
    if (g < 3) {
#pragma unroll
      for (int s = 0; s < 4; ++s)
#pragma unroll
        for (int nt = 0; nt < 2; ++nt)
          B[nxt][s * 2 + nt] = *(const bf16x8*)(
              wb + (size_t)((g + 1) * 4 + s) * 16384 + nt * 512);
    }
#pragma unroll
    for (int s = 0; s < 4; ++s) {
      const int ks = g * 4 + s;
      bf16x8 af0 = *(const bf16x8*)&H_sh[l16 * LDA + ks * 32 + quad * 8];
      bf16x8 af1 =
          *(const bf16x8*)&H_sh[(16 + l16) * LDA + ks * 32 + quad * 8];
#pragma unroll
      for (int nt = 0; nt < 2; ++nt) {
        acc[0][nt] = __builtin_amdgcn_mfma_f32_16x16x32_bf16(
            af0, B[cur][s * 2 + nt], acc[0][nt], 0, 0, 0);
        acc[1][nt] = __builtin_amdgcn_mfma_f32_16x16x32_bf16(
            af1, B[cur][s * 2 + nt], acc[1][nt], 0, 0, 0);
      }
    }
  }

  float vmask[2][4];
#pragma unroll
  for (int m = 0; m < 2; ++m)
#pragma unroll
    for (int r = 0; r < 4; ++r)
      vmask[m][r] = (ridx[m * 16 + quad * 4 + r] >= 0) ? 1.f : 0.f;

#pragma unroll
  for (int nt = 0; nt < 2; ++nt) {
    int col = nq * 128 + w * 32 + nt * 16 + l16;
    float bias = b2[k * DH + col];
    float s = 0.f;
#pragma unroll
    for (int m = 0; m < 2; ++m)
#pragma unroll
      for (int r = 0; r < 4; ++r)
        s += vmask[m][r] * fmaxf(acc[m][nt][r] + bias, 0.f);
    s += __shfl_xor(s, 16, 64);
    s += __shfl_xor(s, 32, 64);
    if (quad == 0) atomicAdd(&psum[k * DH + col], s);
  }
}

// fc (K-batched): H[k][j] = relu(P[k]. @ fcW[:,j] + fcb[j]) for all 10 k at
// once. grid 32 blocks x 256 thr: 16 j-cols x 16 d-chunks of 32.
__global__ __launch_bounds__(256) void fc_kernel(
    const float* __restrict__ psum, const int* __restrict__ cnt,
    const float* __restrict__ fcW, const float* __restrict__ fcb,
    float* __restrict__ hstore) {
  __shared__ float p_sh[KC * DH];       // 20 KB
  __shared__ float invs[16];
  __shared__ float red[16 * 16 * KC];   // 10 KB
  const int tid = threadIdx.x;
  const int j0 = blockIdx.x * 16;
  const int j = tid & 15, dq = tid >> 4;

  if (tid < KC) {
    int c = cnt[tid];
    invs[tid] = (c > 0) ? 1.f / (float)c : 0.f;
  }
  __syncthreads();
#pragma unroll
  for (int it = 0; it < KC * DH / 256; ++it) {
    int e = it * 256 + tid;
    p_sh[e] = psum[e] * invs[e >> 9];
  }
  __syncthreads();

  float acc[KC];
#pragma unroll
  for (int k = 0; k < KC; ++k) acc[k] = 0.f;
#pragma unroll 8
  for (int i = 0; i < 32; ++i) {
    int ii = (i + dq) & 31;             // bank-swizzle across dq
    int d = dq * 32 + ii;
    float wv = fcW[(size_t)d * DH + j0 + j];
#pragma unroll
    for (int k = 0; k < KC; ++k)
      acc[k] = fmaf(p_sh[k * DH + d], wv, acc[k]);
  }
#pragma unroll
  for (int k = 0; k < KC; ++k) red[(dq * 16 + j) * KC + k] = acc[k];
  __syncthreads();
  if (tid < 16 * KC) {
    int jj = tid / KC, k = tid % KC;
    float s = 0.f;
#pragma unroll
    for (int q = 0; q < 16; ++q) s += red[(q * 16 + jj) * KC + k];
    hstore[k * DH + j0 + jj] = fmaxf(s + fcb[j0 + jj], 0.f);
  }
}

// Gated attention (K-batched): s_k = sum_j tanh(H@Va)_kj * sig(H@Vb)_kj * Vc_j.
// grid 16 blocks x 256 thr: 16 j x 16 d-chunks of 32. atomicAdd into sstore.
__global__ __launch_bounds__(256) void attn_kernel(
    const float* __restrict__ hstore, const float* __restrict__ Va,
    const float* __restrict__ ba, const float* __restrict__ Vb,
    const float* __restrict__ bb_, const float* __restrict__ Vc,
    float* __restrict__ sstore) {
  __shared__ float h_sh[KC * DH];        // 20 KB
  __shared__ float reda[16 * 16 * KC];   // 10 KB
  __shared__ float redb[16 * 16 * KC];   // 10 KB
  __shared__ float gred[16 * KC];
  const int tid = threadIdx.x;
  const int j0 = blockIdx.x * 16;
  const int j = tid & 15, dq = tid >> 4;

#pragma unroll
  for (int it = 0; it < KC * DH / 256; ++it) {
    int e = it * 256 + tid;
    h_sh[e] = hstore[e];
  }
  __syncthreads();

  float sa[KC], sb[KC];
#pragma unroll
  for (int k = 0; k < KC; ++k) { sa[k] = 0.f; sb[k] = 0.f; }
#pragma unroll 8
  for (int i = 0; i < 32; ++i) {
    int ii = (i + dq) & 31;
    int d = dq * 32 + ii;
    float va = Va[(size_t)d * DA + j0 + j];
    float vb = Vb[(size_t)d * DA + j0 + j];
#pragma unroll
    for (int k = 0; k < KC; ++k) {
      float h = h_sh[k * DH + d];
      sa[k] = fmaf(h, va, sa[k]);
      sb[k] = fmaf(h, vb, sb[k]);
    }
  }
#pragma unroll
  for (int k = 0; k < KC; ++k) {
    reda[(dq * 16 + j) * KC + k] = sa[k];
    redb[(dq * 16 + j) * KC + k] = sb[k];
  }
  __syncthreads();
  if (tid < 16 * KC) {
    int jj = tid / KC, k = tid % KC;
    float ta = 0.f, tb = 0.f;
#pragma unroll
    for (int q = 0; q < 16; ++q) {
      ta += reda[(q * 16 + jj) * KC + k];
      tb += redb[(q * 16 + jj) * KC + k];
    }
    float a = tanhf(ta + ba[j0 + jj]);
    float b = 1.f / (1.f + expf(-(tb + bb_[j0 + jj])));
    gred[jj * KC + k] = a * b * Vc[j0 + jj];  // bc dropped: softmax shift-inv
  }
  __syncthreads();
  if (tid < KC) {
    float s = 0.f;
#pragma unroll
    for (int jj = 0; jj < 16; ++jj) s += gred[jj * KC + tid];
    atomicAdd(&sstore[tid], s);
  }
}

// rho (split): softmax over sstore + h_path computed redundantly per block,
// then h2 = relu(h_path @ rhoW + rhob) slice. grid 8 blocks x 256 thr:
// 32 j x 8 d-chunks of 64.
__global__ __launch_bounds__(256) void rho_kernel(
    const float* __restrict__ hstore, const float* __restrict__ sstore,
    const float* __restrict__ rhoW, const float* __restrict__ rhob,
    float* __restrict__ h2g) {
  __shared__ float ws_sh[KC];
  __shared__ float hp_sh[DH];
  __shared__ float red[8 * 32];
  const int tid = threadIdx.x;
  const int j0 = blockIdx.x * 32;
  const int j = tid & 31, dq = tid >> 5;

  if (tid == 0) {
    float sv[KC], m = -1e30f;
#pragma unroll
    for (int k = 0; k < KC; ++k) { sv[k] = sstore[k]; m = fmaxf(m, sv[k]); }
    float Z = 0.f;
#pragma unroll
    for (int k = 0; k < KC; ++k) { sv[k] = expf(sv[k] - m); Z += sv[k]; }
    float invZ = 1.f / Z;
#pragma unroll
    for (int k = 0; k < KC; ++k) ws_sh[k] = sv[k] * invZ;
  }
  __syncthreads();
#pragma unroll
  for (int it = 0; it < 2; ++it) {
    int d = it * 256 + tid;
    float s = 0.f;
#pragma unroll
    for (int k = 0; k < KC; ++k) s = fmaf(ws_sh[k], hstore[k * DH + d], s);
    hp_sh[d] = s;
  }
  __syncthreads();

  float acc = 0.f;
#pragma unroll 8
  for (int i = 0; i < 64; ++i) {
    int d = dq * 64 + i;
    acc = fmaf(hp_sh[d], rhoW[(size_t)d * DA + j0 + j], acc);
  }
  red[dq * 32 + j] = acc;
  __syncthreads();
  if (tid < 32) {
    float s = 0.f;
#pragma unroll
    for (int q = 0; q < 8; ++q) s += red[q * 32 + tid];
    h2g[j0 + tid] = fmaxf(s + rhob[j0 + tid], 0.f);
  }
}

// classifier + hazards/S/Y_hat. 1 block.
__global__ __launch_bounds__(256) void cls_kernel(
    const float* __restrict__ h2g, const float* __restrict__ clsW,
    const float* __restrict__ clsb, float* __restrict__ out) {
  __shared__ float rd[NCLS][256];
  const int tid = threadIdx.x;
  float h = h2g[tid];
#pragma unroll
  for (int c = 0; c < NCLS; ++c) rd[c][tid] = h * clsW[tid * NCLS + c];
  __syncthreads();
  for (int s = 128; s > 0; s >>= 1) {
    if (tid < s) {
#pragma unroll
      for (int c = 0; c < NCLS; ++c) rd[c][tid] += rd[c][tid + s];
    }
    __syncthreads();
  }
  if (tid == 0) {
    float lg[NCLS], hz[NCLS];
    int best = 0;
#pragma unroll
    for (int c = 0; c < NCLS; ++c) {
      lg[c] = rd[c][0] + clsb[c];
      hz[c] = 1.f / (1.f + expf(-lg[c]));
      if (lg[c] > lg[best]) best = c;
    }
    float S = 1.f;
#pragma unroll
    for (int c = 0; c < NCLS; ++c) out[c] = hz[c];
#pragma unroll
    for (int c = 0; c < NCLS; ++c) {
      S *= (1.f - hz[c]);
      out[NCLS + c] = S;
    }
    out[2 * NCLS] = (float)best;
  }
}

extern "C" void kernel_launch(void* const* d_in, const int* in_sizes, int n_in,
                              void* d_out, int out_size, void* d_ws,
                              size_t ws_size, hipStream_t stream) {
  const float* x    = (const float*)d_in[0];
  const int*   cid  = (const int*)d_in[1];
  const float* W1   = (const float*)d_in[2];
  const float* b1   = (const float*)d_in[3];
  const float* W2   = (const float*)d_in[4];
  const float* b2   = (const float*)d_in[5];
  const float* fcW  = (const float*)d_in[6];
  const float* fcb  = (const float*)d_in[7];
  const float* Va   = (const float*)d_in[8];
  const float* ba   = (const float*)d_in[9];
  const float* Vb   = (const float*)d_in[10];
  const float* bb_  = (const float*)d_in[11];
  const float* Vc   = (const float*)d_in[12];
  const float* rhoW = (const float*)d_in[14];
  const float* rhob = (const float*)d_in[15];
  const float* clsW = (const float*)d_in[16];
  const float* clsb = (const float*)d_in[17];
  float* out = (float*)d_out;

  char* ws = (char*)d_ws;
  int*   cnt     = (int*)(ws + OFF_CNT);
  int*   idxlist = (int*)(ws + OFF_IDX);
  float* psum    = (float*)(ws + OFF_PSUM);
  float* hstore  = (float*)(ws + OFF_H);
  float* sstore  = (float*)(ws + OFF_S);
  float* h2g     = (float*)(ws + OFF_H2);
  u16*   W1p     = (u16*)(ws + OFF_W1P);
  u16*   W2p     = (u16*)(ws + OFF_W2P);
  u16*   xb      = (u16*)(ws + OFF_XB);
  u16*   h1      = (u16*)(ws + OFF_H1);

  (void)hipMemsetAsync(cnt, 0, 64, stream);
  prep_kernel<<<NB_PREP, 256, 0, stream>>>(cid, cnt, idxlist, W1, W2, W1p, W2p,
                                           x, xb, psum, sstore);
  phi1_kernel<<<dim3(NPATCH / TM, KC, 4), 256, 0, stream>>>(xb, W1p, b1, cnt,
                                                            idxlist, h1);
  phi2_kernel<<<dim3(NPATCH / TM, KC, 4), 256, 0, stream>>>(h1, W2p, b2, cnt,
                                                            idxlist, psum);
  fc_kernel<<<32, 256, 0, stream>>>(psum, cnt, fcW, fcb, hstore);
  attn_kernel<<<16, 256, 0, stream>>>(hstore, Va, ba, Vb, bb_, Vc, sstore);
  rho_kernel<<<8, 256, 0, stream>>>(hstore, sstore, rhoW, rhob, h2g);
  cls_kernel<<<1, 256, 0, stream>>>(h2g, clsW, clsb, out);
}